// Round 8
// baseline (212.873 us; speedup 1.0000x reference)
//
#include <hip/hip_runtime.h>
#include <hip/hip_fp16.h>
#include <math.h>

#define ALPHA_C 0.5f
#define BETA_C  0.5f
#define NPART   256
#define NQUART  4

typedef _Float16 half8 __attribute__((ext_vector_type(8)));
typedef _Float16 half2v __attribute__((ext_vector_type(2)));
typedef float f32x4 __attribute__((ext_vector_type(4)));

// XOR row-swizzle: spreads a column access across 8 LDS bank-groups.
__device__ __forceinline__ int swz(int row, int byteoff) {
    return byteoff ^ ((row & 7) << 4);
}

// One-block prep: W^T in f16, laid out [n][k] so B-fragments are contiguous.
__global__ __launch_bounds__(256) void k_prep(
        const float* __restrict__ W_in, const float* __restrict__ W_out,
        _Float16* __restrict__ w16i, _Float16* __restrict__ w16o) {
    for (int i = threadIdx.x; i < 4096; i += 256) {
        int k = i >> 6, n = i & 63;
        w16o[n * 64 + k] = (_Float16)W_out[k * 64 + n];
        w16i[n * 64 + k] = (_Float16)W_in [k * 64 + n];
    }
}

// Exact degree histogram with NO global atomics (see round-4 notes).
__global__ __launch_bounds__(256) void k_hist(
        const int* __restrict__ eidx, unsigned int* __restrict__ scr,
        int N, int E, int Q, int Wd, int chunk) {
    const int s = blockIdx.x;
    const int role = blockIdx.y;
    const int dir = role & 1;
    const int q = role >> 1;
    extern __shared__ unsigned int lds[];          // Wd words
    for (int w = threadIdx.x; w < Wd; w += blockDim.x) lds[w] = 0;
    __syncthreads();
    const int base = q * Q;
    const int hi = min(N - base, Q);               // nodes in this quarter
    const int* __restrict__ arr = eidx + (size_t)dir * E;
    const int start = s * chunk;
    const int end = min(E, start + chunk);
    const int4* __restrict__ a4 = (const int4*)arr;
    const int v1 = end >> 2;
    for (int v = (start >> 2) + threadIdx.x; v < v1; v += blockDim.x) {
        int4 x = a4[v];
        int l;
        l = x.x - base; if ((unsigned)l < (unsigned)hi) atomicAdd(&lds[l >> 1], 1u << ((l & 1) * 16));
        l = x.y - base; if ((unsigned)l < (unsigned)hi) atomicAdd(&lds[l >> 1], 1u << ((l & 1) * 16));
        l = x.z - base; if ((unsigned)l < (unsigned)hi) atomicAdd(&lds[l >> 1], 1u << ((l & 1) * 16));
        l = x.w - base; if ((unsigned)l < (unsigned)hi) atomicAdd(&lds[l >> 1], 1u << ((l & 1) * 16));
    }
    for (int i = (v1 << 2) + threadIdx.x; i < end; i += blockDim.x) {
        int l = arr[i] - base;
        if ((unsigned)l < (unsigned)hi) atomicAdd(&lds[l >> 1], 1u << ((l & 1) * 16));
    }
    __syncthreads();
    unsigned int* __restrict__ dst = scr + ((size_t)role * gridDim.x + s) * Wd;
    for (int w = threadIdx.x; w < Wd; w += blockDim.x) dst[w] = lds[w];
}

// Fold slice histograms -> float degrees + sum-of-squares partials.
__global__ __launch_bounds__(256) void k_fold(
        const unsigned int* __restrict__ scr,
        float* __restrict__ deg_out, float* __restrict__ deg_in,
        float* __restrict__ partials, int N, int Q, int Wd, int S) {
    float so = 0.f, si = 0.f;
    for (int n = blockIdx.x * blockDim.x + threadIdx.x; n < N;
         n += gridDim.x * blockDim.x) {
        const int q = n / Q, l = n - q * Q;
        const int w = l >> 1, sh = (l & 1) * 16;
        const unsigned int* __restrict__ p0 = scr + ((size_t)(q * 2 + 0) * S) * Wd + w;
        const unsigned int* __restrict__ p1 = scr + ((size_t)(q * 2 + 1) * S) * Wd + w;
        unsigned int a = 0, b = 0;
        for (int s = 0; s < S; ++s) {
            a += (p0[(size_t)s * Wd] >> sh) & 0xFFFFu;
            b += (p1[(size_t)s * Wd] >> sh) & 0xFFFFu;
        }
        float fa = (float)a, fb = (float)b;
        deg_out[n] = fa;
        deg_in[n] = fb;
        so = fmaf(fa, fa, so);
        si = fmaf(fb, fb, si);
    }
#pragma unroll
    for (int off = 32; off; off >>= 1) {
        so += __shfl_xor(so, off);
        si += __shfl_xor(si, off);
    }
    __shared__ float sm[2][4];
    int lane = threadIdx.x & 63, w = threadIdx.x >> 6;
    if (lane == 0) { sm[0][w] = so; sm[1][w] = si; }
    __syncthreads();
    if (threadIdx.x == 0) {
        partials[blockIdx.x]         = sm[0][0] + sm[0][1] + sm[0][2] + sm[0][3];
        partials[NPART + blockIdx.x] = sm[1][0] + sm[1][1] + sm[1][2] + sm[1][3];
    }
}

__global__ __launch_bounds__(256) void k_finish(
        const float* __restrict__ partials, float* __restrict__ inv_nrm) {
    int t = threadIdx.x;
    float so = partials[t], si = partials[NPART + t];
#pragma unroll
    for (int off = 32; off; off >>= 1) {
        so += __shfl_xor(so, off);
        si += __shfl_xor(si, off);
    }
    __shared__ float sm[2][4];
    int lane = t & 63, w = t >> 6;
    if (lane == 0) { sm[0][w] = so; sm[1][w] = si; }
    __syncthreads();
    if (t == 0) {
        float a = sm[0][0] + sm[0][1] + sm[0][2] + sm[0][3];
        float b = sm[1][0] + sm[1][1] + sm[1][2] + sm[1][3];
        inv_nrm[0] = (a > 0.f) ? rsqrtf(a) : 0.f;
        inv_nrm[1] = (b > 0.f) ? rsqrtf(b) : 0.f;
    }
}

// MFMA node precompute. Same verified fragment maps as round 6/7:
//   A[m][k]: m = lane&15, k = 32*s + 8*(lane>>4) + j
//   B[k][n]: n = lane&15, k = 32*s + 8*(lane>>4) + j  (from w16 = W^T [n][k])
//   D[m][n]: n = lane&15, m = 4*(lane>>4) + reg
// z tiles staged in LDS (coalesced); B-fragments straight from the 8 KB
// L1-resident w16 arrays; P-tile epilogue identical to round 7.
__global__ __launch_bounds__(256) void k_nodes(
        const float* __restrict__ z_in, const float* __restrict__ z_out,
        const float* __restrict__ z_self,
        const _Float16* __restrict__ w16i, const _Float16* __restrict__ w16o,
        const float* __restrict__ b_in, const float* __restrict__ b_out,
        const float* __restrict__ deg_out, const float* __restrict__ deg_in,
        const float* __restrict__ inv_nrm,
        _Float16* __restrict__ P_src, _Float16* __restrict__ P_dst,
        float* __restrict__ s_src, float* __restrict__ s_dst, int N) {
    __shared__ _Float16 smem[16384];                 // 32 KB
    char* lzo = (char*)smem;                         // [64][64] f16, 8 KB
    char* lzi = (char*)smem + 8192;
    char* lps = (char*)smem;                         // [64][128] f16 (aliases z)
    char* lpd = (char*)smem + 16384;

    const int tid = threadIdx.x;
    const int lane = tid & 63;
    const int wid = tid >> 6;
    const int r = lane & 15, g = lane >> 4;
    const int base = blockIdx.x * 64;
    const int wrow = wid * 16;

    // ---- phase 1: stage z tiles into LDS (coalesced reads) ----
#pragma unroll
    for (int it = 0; it < 8; ++it) {
        int flat = it * 256 + tid;                   // [0, 2048)
        int row = flat >> 5;                         // 0..63
        int c2 = (flat & 31) * 2;                    // even col
        int grow = min(base + row, N - 1);
        const float* zr = z_out + (size_t)grow * 65;
        half2v ho = { (_Float16)zr[c2], (_Float16)zr[c2 + 1] };
        *(half2v*)(lzo + row * 128 + swz(row, c2 * 2)) = ho;
        const float* zr2 = z_in + (size_t)grow * 65;
        half2v hi = { (_Float16)zr2[c2], (_Float16)zr2[c2 + 1] };
        *(half2v*)(lzi + row * 128 + swz(row, c2 * 2)) = hi;
    }
    // bias fragments (256 B f32 arrays, L1-hot; only col-0 lanes nonzero)
    half8 bO[2], bI[2];
#pragma unroll
    for (int s = 0; s < 2; ++s)
#pragma unroll
        for (int j = 0; j < 8; ++j) {
            int k = 32 * s + 8 * g + j;
            bO[s][j] = (r == 0) ? (_Float16)b_out[k] : (_Float16)0.f;
            bI[s][j] = (r == 0) ? (_Float16)b_in [k] : (_Float16)0.f;
        }
    __syncthreads();

    // ---- phase 2: A from LDS, B direct from global (L1), MFMA ----
    half8 AO[2], AI[2];
#pragma unroll
    for (int s = 0; s < 2; ++s) {
        int arow = wrow + r;
        int off = arow * 128 + swz(arow, s * 64 + g * 16);
        AO[s] = *(half8*)(lzo + off);
        AI[s] = *(half8*)(lzi + off);
    }
    f32x4 aO[4], aI[4], abO = (f32x4)0.f, abI = (f32x4)0.f;
#pragma unroll
    for (int t = 0; t < 4; ++t) { aO[t] = (f32x4)0.f; aI[t] = (f32x4)0.f; }
#pragma unroll
    for (int s = 0; s < 2; ++s) {
#pragma unroll
        for (int t = 0; t < 4; ++t) {
            int woff = (16 * t + r) * 64 + 32 * s + 8 * g;
            half8 BO = *(const half8*)(w16o + woff);
            aO[t] = __builtin_amdgcn_mfma_f32_16x16x32_f16(AO[s], BO, aO[t], 0, 0, 0);
            half8 BI = *(const half8*)(w16i + woff);
            aI[t] = __builtin_amdgcn_mfma_f32_16x16x32_f16(AI[s], BI, aI[t], 0, 0, 0);
        }
        abO = __builtin_amdgcn_mfma_f32_16x16x32_f16(AO[s], bO[s], abO, 0, 0, 0);
        abI = __builtin_amdgcn_mfma_f32_16x16x32_f16(AI[s], bI[s], abI, 0, 0, 0);
    }
    __syncthreads();   // z tiles dead; lps aliases them

    // ---- phase 3: results + z_self into swizzled LDS P-tiles ----
#pragma unroll
    for (int t = 0; t < 4; ++t)
#pragma unroll
        for (int rr = 0; rr < 4; ++rr) {
            int lrow = wrow + 4 * g + rr;
            int col2 = (16 * t + r) * 2;
            *(_Float16*)(lps + lrow * 256 + swz(lrow, col2)) = (_Float16)aO[t][rr];
            *(_Float16*)(lpd + lrow * 256 + swz(lrow, 128 + col2)) = (_Float16)aI[t][rr];
        }
#pragma unroll
    for (int it = 0; it < 8; ++it) {
        int flat = it * 256 + tid;
        int row = flat >> 5;
        int c2 = (flat & 31) * 2;
        int grow = min(base + row, N - 1);
        float2 v = *(const float2*)(z_self + (size_t)grow * 64 + c2);
        half2v h = { (_Float16)v.x, (_Float16)v.y };
        *(half2v*)(lps + row * 256 + swz(row, 128 + c2 * 2)) = h;   // P_src[,64:]
        *(half2v*)(lpd + row * 256 + swz(row, c2 * 2)) = h;         // P_dst[,:64]
    }
    // per-node scalars from the bias-dot accumulators (col-0 lanes)
    if (r == 0) {
        const float i0 = inv_nrm[0], i1 = inv_nrm[1];
#pragma unroll
        for (int rr = 0; rr < 4; ++rr) {
            int m = base + wrow + 4 * g + rr;
            if (m < N) {
                s_src[m] = BETA_C * fmaf(deg_out[m], i0, z_out[(size_t)m * 65 + 64])
                         + ALPHA_C * abO[rr];
                s_dst[m] = BETA_C * fmaf(deg_in[m],  i1, z_in [(size_t)m * 65 + 64])
                         + ALPHA_C * abI[rr];
            }
        }
    }
    __syncthreads();

    // ---- phase 4: coalesced 16B/lane flush to global ----
#pragma unroll
    for (int it = 0; it < 4; ++it) {
        int lrow = it * 16 + (tid >> 4);
        int seg = tid & 15;
        int m = base + lrow;
        if (m < N) {
            half8 v = *(half8*)(lps + lrow * 256 + swz(lrow, seg * 16));
            *(half8*)(P_src + (size_t)m * 128 + seg * 8) = v;
            half8 v2 = *(half8*)(lpd + lrow * 256 + swz(lrow, seg * 16));
            *(half8*)(P_dst + (size_t)m * 128 + seg * 8) = v2;
        }
    }
}

// Per-edge: 16 lanes per TWO edges (4x 16B gathers in flight per lane),
// fp16 dot via v_dot2_f32_f16. Scalar s-gathers hoisted before the dot.
__global__ __launch_bounds__(256) void k_edges(
        const int* __restrict__ eidx,
        const _Float16* __restrict__ P_src, const _Float16* __restrict__ P_dst,
        const float* __restrict__ s_src, const float* __restrict__ s_dst,
        float* __restrict__ out, int E) {
    const int sub = threadIdx.x & 15;
    const int grp = blockIdx.x * (blockDim.x >> 4) + (threadIdx.x >> 4);
    const int e0 = grp << 1;
    if (e0 >= E) return;
    const bool has1 = (e0 + 1) < E;
    int2 ss = *(const int2*)(eidx + e0);
    int2 dd = *(const int2*)(eidx + E + e0);
    const int s1 = has1 ? ss.y : ss.x, d1 = has1 ? dd.y : dd.x;
    const uint4 a0 = *(const uint4*)(P_src + (size_t)ss.x * 128 + sub * 8);
    const uint4 b0 = *(const uint4*)(P_dst + (size_t)dd.x * 128 + sub * 8);
    const uint4 a1 = *(const uint4*)(P_src + (size_t)s1 * 128 + sub * 8);
    const uint4 b1 = *(const uint4*)(P_dst + (size_t)d1 * 128 + sub * 8);
    float ssum = 0.f;
    if (sub < 2) {
        int s = sub ? s1 : ss.x;
        int d = sub ? d1 : dd.x;
        ssum = s_src[s] + s_dst[d];
    }
    float acc0 = 0.f, acc1 = 0.f;
    acc0 = __builtin_amdgcn_fdot2(__builtin_bit_cast(half2v, a0.x), __builtin_bit_cast(half2v, b0.x), acc0, false);
    acc0 = __builtin_amdgcn_fdot2(__builtin_bit_cast(half2v, a0.y), __builtin_bit_cast(half2v, b0.y), acc0, false);
    acc0 = __builtin_amdgcn_fdot2(__builtin_bit_cast(half2v, a0.z), __builtin_bit_cast(half2v, b0.z), acc0, false);
    acc0 = __builtin_amdgcn_fdot2(__builtin_bit_cast(half2v, a0.w), __builtin_bit_cast(half2v, b0.w), acc0, false);
    acc1 = __builtin_amdgcn_fdot2(__builtin_bit_cast(half2v, a1.x), __builtin_bit_cast(half2v, b1.x), acc1, false);
    acc1 = __builtin_amdgcn_fdot2(__builtin_bit_cast(half2v, a1.y), __builtin_bit_cast(half2v, b1.y), acc1, false);
    acc1 = __builtin_amdgcn_fdot2(__builtin_bit_cast(half2v, a1.z), __builtin_bit_cast(half2v, b1.z), acc1, false);
    acc1 = __builtin_amdgcn_fdot2(__builtin_bit_cast(half2v, a1.w), __builtin_bit_cast(half2v, b1.w), acc1, false);
#pragma unroll
    for (int off = 8; off; off >>= 1) {
        acc0 += __shfl_xor(acc0, off);
        acc1 += __shfl_xor(acc1, off);
    }
    if (sub < 2 && (sub == 0 || has1)) {
        float acc = sub ? acc1 : acc0;
        float v = fmaf(ALPHA_C, acc, ssum);
        out[e0 + sub] = 1.0f / (1.0f + __expf(-v));
    }
}

extern "C" void kernel_launch(void* const* d_in, const int* in_sizes, int n_in,
                              void* d_out, int out_size, void* d_ws, size_t ws_size,
                              hipStream_t stream) {
    const float* z_in   = (const float*)d_in[0];
    const float* z_out  = (const float*)d_in[1];
    const float* z_self = (const float*)d_in[2];
    const float* W_in   = (const float*)d_in[3];
    const float* b_in   = (const float*)d_in[4];
    const float* W_out  = (const float*)d_in[5];
    const float* b_out  = (const float*)d_in[6];
    const int*   eidx   = (const int*)d_in[7];

    const int N = in_sizes[2] / 64;   // z_self is [N, 64]
    const int E = in_sizes[7] / 2;    // edge_index is [2, E]

    // Histogram geometry: per-slice edge count < 65536 => u16-exact.
    const int Q = (N + NQUART - 1) / NQUART;          // nodes per quarter
    const int Wd = (Q + 1) / 2;                       // packed u32 words
    int S = (E + 49999) / 50000;                      // slices
    if (S < 1) S = 1;
    int chunk = ((E + S - 1) / S + 3) & ~3;           // mult of 4, < 65536

    float* ws       = (float*)d_ws;
    float* deg_out  = ws;                             // N
    float* deg_in   = ws + (size_t)N;                 // N
    float* s_src    = ws + 2 * (size_t)N;             // N
    float* s_dst    = ws + 3 * (size_t)N;             // N
    _Float16* P_src = (_Float16*)(ws + 4 * (size_t)N);        // N*128 fp16
    _Float16* P_dst = P_src + (size_t)N * 128;                // N*128 fp16
    float* partials = (float*)(P_dst + (size_t)N * 128);      // 2*NPART
    float* inv_nrm  = partials + 2 * NPART;                   // 2
    _Float16* w16o  = (_Float16*)(partials + 2 * NPART + 16); // 4096 f16 (16B-aligned)
    _Float16* w16i  = w16o + 4096;                            // 4096 f16
    // Slice histograms (~12.8 MB) alias the P_src region (25.6 MB): dead
    // before k_nodes writes P_src/P_dst.
    unsigned int* scr = (unsigned int*)P_src;

    k_prep<<<1, 256, 0, stream>>>(W_in, W_out, w16i, w16o);
    dim3 hgrid(S, 2 * NQUART);
    k_hist<<<hgrid, 256, (size_t)Wd * 4, stream>>>(eidx, scr, N, E, Q, Wd, chunk);
    k_fold<<<NPART, 256, 0, stream>>>(scr, deg_out, deg_in, partials, N, Q, Wd, S);
    k_finish<<<1, 256, 0, stream>>>(partials, inv_nrm);
    k_nodes<<<(N + 63) / 64, 256, 0, stream>>>(z_in, z_out, z_self, w16i, w16o,
                                               b_in, b_out, deg_out, deg_in,
                                               inv_nrm, P_src, P_dst,
                                               s_src, s_dst, N);
    {
        int groups = (E + 1) / 2;
        int blocks = (groups + 15) / 16;
        k_edges<<<blocks, 256, 0, stream>>>(eidx, P_src, P_dst,
                                            s_src, s_dst, (float*)d_out, E);
    }
}

// Round 9
// 209.459 us; speedup vs baseline: 1.0163x; 1.0163x over previous
//
#include <hip/hip_runtime.h>
#include <hip/hip_fp16.h>
#include <math.h>

#define ALPHA_C 0.5f
#define BETA_C  0.5f
#define NPART   256
#define NQUART  4

typedef _Float16 half8 __attribute__((ext_vector_type(8)));
typedef _Float16 half2v __attribute__((ext_vector_type(2)));
typedef float f32x4 __attribute__((ext_vector_type(4)));

// XOR row-swizzle: spreads a column access across 8 LDS bank-groups.
__device__ __forceinline__ int swz(int row, int byteoff) {
    return byteoff ^ ((row & 7) << 4);
}
// 16B load tolerant of 4B alignment (z rows have stride 65 f32).
__device__ __forceinline__ float4 ldg16u(const float* p) {
    float4 v; __builtin_memcpy(&v, p, 16); return v;
}

// Exact degree histogram with NO global atomics (see round-4 notes).
__global__ __launch_bounds__(256) void k_hist(
        const int* __restrict__ eidx, unsigned int* __restrict__ scr,
        int N, int E, int Q, int Wd, int chunk) {
    const int s = blockIdx.x;
    const int role = blockIdx.y;
    const int dir = role & 1;
    const int q = role >> 1;
    extern __shared__ unsigned int lds[];          // Wd words
    for (int w = threadIdx.x; w < Wd; w += blockDim.x) lds[w] = 0;
    __syncthreads();
    const int base = q * Q;
    const int hi = min(N - base, Q);               // nodes in this quarter
    const int* __restrict__ arr = eidx + (size_t)dir * E;
    const int start = s * chunk;
    const int end = min(E, start + chunk);
    const int4* __restrict__ a4 = (const int4*)arr;
    const int v1 = end >> 2;
    for (int v = (start >> 2) + threadIdx.x; v < v1; v += blockDim.x) {
        int4 x = a4[v];
        int l;
        l = x.x - base; if ((unsigned)l < (unsigned)hi) atomicAdd(&lds[l >> 1], 1u << ((l & 1) * 16));
        l = x.y - base; if ((unsigned)l < (unsigned)hi) atomicAdd(&lds[l >> 1], 1u << ((l & 1) * 16));
        l = x.z - base; if ((unsigned)l < (unsigned)hi) atomicAdd(&lds[l >> 1], 1u << ((l & 1) * 16));
        l = x.w - base; if ((unsigned)l < (unsigned)hi) atomicAdd(&lds[l >> 1], 1u << ((l & 1) * 16));
    }
    for (int i = (v1 << 2) + threadIdx.x; i < end; i += blockDim.x) {
        int l = arr[i] - base;
        if ((unsigned)l < (unsigned)hi) atomicAdd(&lds[l >> 1], 1u << ((l & 1) * 16));
    }
    __syncthreads();
    unsigned int* __restrict__ dst = scr + ((size_t)role * gridDim.x + s) * Wd;
    for (int w = threadIdx.x; w < Wd; w += blockDim.x) dst[w] = lds[w];
}

// Fold slice histograms -> float degrees + sum-of-squares partials.
__global__ __launch_bounds__(256) void k_fold(
        const unsigned int* __restrict__ scr,
        float* __restrict__ deg_out, float* __restrict__ deg_in,
        float* __restrict__ partials, int N, int Q, int Wd, int S) {
    float so = 0.f, si = 0.f;
    for (int n = blockIdx.x * blockDim.x + threadIdx.x; n < N;
         n += gridDim.x * blockDim.x) {
        const int q = n / Q, l = n - q * Q;
        const int w = l >> 1, sh = (l & 1) * 16;
        const unsigned int* __restrict__ p0 = scr + ((size_t)(q * 2 + 0) * S) * Wd + w;
        const unsigned int* __restrict__ p1 = scr + ((size_t)(q * 2 + 1) * S) * Wd + w;
        unsigned int a = 0, b = 0;
        for (int s = 0; s < S; ++s) {
            a += (p0[(size_t)s * Wd] >> sh) & 0xFFFFu;
            b += (p1[(size_t)s * Wd] >> sh) & 0xFFFFu;
        }
        float fa = (float)a, fb = (float)b;
        deg_out[n] = fa;
        deg_in[n] = fb;
        so = fmaf(fa, fa, so);
        si = fmaf(fb, fb, si);
    }
#pragma unroll
    for (int off = 32; off; off >>= 1) {
        so += __shfl_xor(so, off);
        si += __shfl_xor(si, off);
    }
    __shared__ float sm[2][4];
    int lane = threadIdx.x & 63, w = threadIdx.x >> 6;
    if (lane == 0) { sm[0][w] = so; sm[1][w] = si; }
    __syncthreads();
    if (threadIdx.x == 0) {
        partials[blockIdx.x]         = sm[0][0] + sm[0][1] + sm[0][2] + sm[0][3];
        partials[NPART + blockIdx.x] = sm[1][0] + sm[1][1] + sm[1][2] + sm[1][3];
    }
}

// Finish the norm reduction AND build the f16 W^T arrays (absorbs old k_prep).
__global__ __launch_bounds__(256) void k_finish(
        const float* __restrict__ partials, float* __restrict__ inv_nrm,
        const float* __restrict__ W_in, const float* __restrict__ W_out,
        _Float16* __restrict__ w16i, _Float16* __restrict__ w16o) {
    int t = threadIdx.x;
    for (int i = t; i < 4096; i += 256) {
        int k = i >> 6, n = i & 63;
        w16o[n * 64 + k] = (_Float16)W_out[k * 64 + n];
        w16i[n * 64 + k] = (_Float16)W_in [k * 64 + n];
    }
    float so = partials[t], si = partials[NPART + t];
#pragma unroll
    for (int off = 32; off; off >>= 1) {
        so += __shfl_xor(so, off);
        si += __shfl_xor(si, off);
    }
    __shared__ float sm[2][4];
    int lane = t & 63, w = t >> 6;
    if (lane == 0) { sm[0][w] = so; sm[1][w] = si; }
    __syncthreads();
    if (t == 0) {
        float a = sm[0][0] + sm[0][1] + sm[0][2] + sm[0][3];
        float b = sm[1][0] + sm[1][1] + sm[1][2] + sm[1][3];
        inv_nrm[0] = (a > 0.f) ? rsqrtf(a) : 0.f;
        inv_nrm[1] = (b > 0.f) ? rsqrtf(b) : 0.f;
    }
}

// MFMA node precompute, zero staging. Verified fragment maps (rounds 5-8):
//   A[m][k]: m = lane&15, k = 32*s + 8*(lane>>4) + j    (direct global loads)
//   B[k][n]: n = lane&15, k = 32*s + 8*(lane>>4) + j    (w16 = W^T [n][k], regs)
//   D[m][n]: n = lane&15, m = 4*(lane>>4) + reg
// LDS is ONLY the swizzled P-tile epilogue; single __syncthreads.
__global__ __launch_bounds__(256) void k_nodes(
        const float* __restrict__ z_in, const float* __restrict__ z_out,
        const float* __restrict__ z_self,
        const _Float16* __restrict__ w16i, const _Float16* __restrict__ w16o,
        const float* __restrict__ b_in, const float* __restrict__ b_out,
        const float* __restrict__ deg_out, const float* __restrict__ deg_in,
        const float* __restrict__ inv_nrm,
        _Float16* __restrict__ P_src, _Float16* __restrict__ P_dst,
        float* __restrict__ s_src, float* __restrict__ s_dst, int N) {
    __shared__ _Float16 smem[16384];              // 32 KB: two [64]x256B P tiles
    char* lps = (char*)smem;
    char* lpd = (char*)smem + 16384;

    const int tid = threadIdx.x;
    const int lane = tid & 63;
    const int wid = tid >> 6;
    const int r = lane & 15, g = lane >> 4;
    const int base = blockIdx.x * 64;
    const int wrow = wid * 16;
    const int arow = min(base + wrow + r, N - 1);   // this lane's A row
    const int colk = 8 * g;                          // k-offset within 32-chunk

    // z_self staging into registers (block-wide coalesced, issued early)
    float2 zsv[8];
#pragma unroll
    for (int it = 0; it < 8; ++it) {
        int flat = it * 256 + tid;
        int row = flat >> 5;
        int c2 = (flat & 31) * 2;
        int grow = min(base + row, N - 1);
        zsv[it] = *(const float2*)(z_self + (size_t)grow * 64 + c2);
    }
    const float i0 = inv_nrm[0], i1 = inv_nrm[1];

    // ---------------- OUT matrix:  v_out -> P_src[:,0:64], s_src ----------
    {
        half8 B[2][4], bb[2], A[2];
#pragma unroll
        for (int s = 0; s < 2; ++s) {
#pragma unroll
            for (int t = 0; t < 4; ++t)
                B[s][t] = *(const half8*)(w16o + (16 * t + r) * 64 + 32 * s + colk);
#pragma unroll
            for (int j = 0; j < 8; ++j)
                bb[s][j] = (r == 0) ? (_Float16)b_out[32 * s + colk + j] : (_Float16)0.f;
            float4 lo = ldg16u(z_out + (size_t)arow * 65 + 32 * s + colk);
            float4 hi = ldg16u(z_out + (size_t)arow * 65 + 32 * s + colk + 4);
            A[s][0] = (_Float16)lo.x; A[s][1] = (_Float16)lo.y;
            A[s][2] = (_Float16)lo.z; A[s][3] = (_Float16)lo.w;
            A[s][4] = (_Float16)hi.x; A[s][5] = (_Float16)hi.y;
            A[s][6] = (_Float16)hi.z; A[s][7] = (_Float16)hi.w;
        }
        f32x4 acc[4], accb = (f32x4)0.f;
#pragma unroll
        for (int t = 0; t < 4; ++t) acc[t] = (f32x4)0.f;
#pragma unroll
        for (int s = 0; s < 2; ++s) {
#pragma unroll
            for (int t = 0; t < 4; ++t)
                acc[t] = __builtin_amdgcn_mfma_f32_16x16x32_f16(A[s], B[s][t], acc[t], 0, 0, 0);
            accb = __builtin_amdgcn_mfma_f32_16x16x32_f16(A[s], bb[s], accb, 0, 0, 0);
        }
#pragma unroll
        for (int t = 0; t < 4; ++t)
#pragma unroll
            for (int rr = 0; rr < 4; ++rr) {
                int lrow = wrow + 4 * g + rr;
                *(_Float16*)(lps + lrow * 256 + swz(lrow, (16 * t + r) * 2)) =
                    (_Float16)acc[t][rr];
            }
        if (r == 0) {
#pragma unroll
            for (int rr = 0; rr < 4; ++rr) {
                int m = base + wrow + 4 * g + rr;
                if (m < N)
                    s_src[m] = BETA_C * fmaf(deg_out[m], i0, z_out[(size_t)m * 65 + 64])
                             + ALPHA_C * accb[rr];
            }
        }
    }

    // ---------------- IN matrix:  v_in -> P_dst[:,64:128], s_dst ----------
    {
        half8 B[2][4], bb[2], A[2];
#pragma unroll
        for (int s = 0; s < 2; ++s) {
#pragma unroll
            for (int t = 0; t < 4; ++t)
                B[s][t] = *(const half8*)(w16i + (16 * t + r) * 64 + 32 * s + colk);
#pragma unroll
            for (int j = 0; j < 8; ++j)
                bb[s][j] = (r == 0) ? (_Float16)b_in[32 * s + colk + j] : (_Float16)0.f;
            float4 lo = ldg16u(z_in + (size_t)arow * 65 + 32 * s + colk);
            float4 hi = ldg16u(z_in + (size_t)arow * 65 + 32 * s + colk + 4);
            A[s][0] = (_Float16)lo.x; A[s][1] = (_Float16)lo.y;
            A[s][2] = (_Float16)lo.z; A[s][3] = (_Float16)lo.w;
            A[s][4] = (_Float16)hi.x; A[s][5] = (_Float16)hi.y;
            A[s][6] = (_Float16)hi.z; A[s][7] = (_Float16)hi.w;
        }
        f32x4 acc[4], accb = (f32x4)0.f;
#pragma unroll
        for (int t = 0; t < 4; ++t) acc[t] = (f32x4)0.f;
#pragma unroll
        for (int s = 0; s < 2; ++s) {
#pragma unroll
            for (int t = 0; t < 4; ++t)
                acc[t] = __builtin_amdgcn_mfma_f32_16x16x32_f16(A[s], B[s][t], acc[t], 0, 0, 0);
            accb = __builtin_amdgcn_mfma_f32_16x16x32_f16(A[s], bb[s], accb, 0, 0, 0);
        }
#pragma unroll
        for (int t = 0; t < 4; ++t)
#pragma unroll
            for (int rr = 0; rr < 4; ++rr) {
                int lrow = wrow + 4 * g + rr;
                *(_Float16*)(lpd + lrow * 256 + swz(lrow, 128 + (16 * t + r) * 2)) =
                    (_Float16)acc[t][rr];
            }
        if (r == 0) {
#pragma unroll
            for (int rr = 0; rr < 4; ++rr) {
                int m = base + wrow + 4 * g + rr;
                if (m < N)
                    s_dst[m] = BETA_C * fmaf(deg_in[m], i1, z_in[(size_t)m * 65 + 64])
                             + ALPHA_C * accb[rr];
            }
        }
    }

    // z_self halves into both P tiles (from registers)
#pragma unroll
    for (int it = 0; it < 8; ++it) {
        int flat = it * 256 + tid;
        int row = flat >> 5;
        int c2 = (flat & 31) * 2;
        half2v h = { (_Float16)zsv[it].x, (_Float16)zsv[it].y };
        *(half2v*)(lps + row * 256 + swz(row, 128 + c2 * 2)) = h;   // P_src[,64:]
        *(half2v*)(lpd + row * 256 + swz(row, c2 * 2)) = h;         // P_dst[,:64]
    }
    __syncthreads();

    // coalesced 16B/lane flush to global
#pragma unroll
    for (int it = 0; it < 4; ++it) {
        int lrow = it * 16 + (tid >> 4);
        int seg = tid & 15;
        int m = base + lrow;
        if (m < N) {
            half8 v = *(half8*)(lps + lrow * 256 + swz(lrow, seg * 16));
            *(half8*)(P_src + (size_t)m * 128 + seg * 8) = v;
            half8 v2 = *(half8*)(lpd + lrow * 256 + swz(lrow, seg * 16));
            *(half8*)(P_dst + (size_t)m * 128 + seg * 8) = v2;
        }
    }
}

// Per-edge: 16 lanes per TWO edges (4x 16B gathers in flight per lane),
// fp16 dot via v_dot2_f32_f16. Scalar s-gathers hoisted before the dot.
__global__ __launch_bounds__(256) void k_edges(
        const int* __restrict__ eidx,
        const _Float16* __restrict__ P_src, const _Float16* __restrict__ P_dst,
        const float* __restrict__ s_src, const float* __restrict__ s_dst,
        float* __restrict__ out, int E) {
    const int sub = threadIdx.x & 15;
    const int grp = blockIdx.x * (blockDim.x >> 4) + (threadIdx.x >> 4);
    const int e0 = grp << 1;
    if (e0 >= E) return;
    const bool has1 = (e0 + 1) < E;
    int2 ss = *(const int2*)(eidx + e0);
    int2 dd = *(const int2*)(eidx + E + e0);
    const int s1 = has1 ? ss.y : ss.x, d1 = has1 ? dd.y : dd.x;
    const uint4 a0 = *(const uint4*)(P_src + (size_t)ss.x * 128 + sub * 8);
    const uint4 b0 = *(const uint4*)(P_dst + (size_t)dd.x * 128 + sub * 8);
    const uint4 a1 = *(const uint4*)(P_src + (size_t)s1 * 128 + sub * 8);
    const uint4 b1 = *(const uint4*)(P_dst + (size_t)d1 * 128 + sub * 8);
    float ssum = 0.f;
    if (sub < 2) {
        int s = sub ? s1 : ss.x;
        int d = sub ? d1 : dd.x;
        ssum = s_src[s] + s_dst[d];
    }
    float acc0 = 0.f, acc1 = 0.f;
    acc0 = __builtin_amdgcn_fdot2(__builtin_bit_cast(half2v, a0.x), __builtin_bit_cast(half2v, b0.x), acc0, false);
    acc0 = __builtin_amdgcn_fdot2(__builtin_bit_cast(half2v, a0.y), __builtin_bit_cast(half2v, b0.y), acc0, false);
    acc0 = __builtin_amdgcn_fdot2(__builtin_bit_cast(half2v, a0.z), __builtin_bit_cast(half2v, b0.z), acc0, false);
    acc0 = __builtin_amdgcn_fdot2(__builtin_bit_cast(half2v, a0.w), __builtin_bit_cast(half2v, b0.w), acc0, false);
    acc1 = __builtin_amdgcn_fdot2(__builtin_bit_cast(half2v, a1.x), __builtin_bit_cast(half2v, b1.x), acc1, false);
    acc1 = __builtin_amdgcn_fdot2(__builtin_bit_cast(half2v, a1.y), __builtin_bit_cast(half2v, b1.y), acc1, false);
    acc1 = __builtin_amdgcn_fdot2(__builtin_bit_cast(half2v, a1.z), __builtin_bit_cast(half2v, b1.z), acc1, false);
    acc1 = __builtin_amdgcn_fdot2(__builtin_bit_cast(half2v, a1.w), __builtin_bit_cast(half2v, b1.w), acc1, false);
#pragma unroll
    for (int off = 8; off; off >>= 1) {
        acc0 += __shfl_xor(acc0, off);
        acc1 += __shfl_xor(acc1, off);
    }
    if (sub < 2 && (sub == 0 || has1)) {
        float acc = sub ? acc1 : acc0;
        float v = fmaf(ALPHA_C, acc, ssum);
        out[e0 + sub] = 1.0f / (1.0f + __expf(-v));
    }
}

extern "C" void kernel_launch(void* const* d_in, const int* in_sizes, int n_in,
                              void* d_out, int out_size, void* d_ws, size_t ws_size,
                              hipStream_t stream) {
    const float* z_in   = (const float*)d_in[0];
    const float* z_out  = (const float*)d_in[1];
    const float* z_self = (const float*)d_in[2];
    const float* W_in   = (const float*)d_in[3];
    const float* b_in   = (const float*)d_in[4];
    const float* W_out  = (const float*)d_in[5];
    const float* b_out  = (const float*)d_in[6];
    const int*   eidx   = (const int*)d_in[7];

    const int N = in_sizes[2] / 64;   // z_self is [N, 64]
    const int E = in_sizes[7] / 2;    // edge_index is [2, E]

    // Histogram geometry: per-slice edge count < 65536 => u16-exact.
    const int Q = (N + NQUART - 1) / NQUART;          // nodes per quarter
    const int Wd = (Q + 1) / 2;                       // packed u32 words
    int S = (E + 49999) / 50000;                      // slices
    if (S < 1) S = 1;
    int chunk = ((E + S - 1) / S + 3) & ~3;           // mult of 4, < 65536

    float* ws       = (float*)d_ws;
    float* deg_out  = ws;                             // N
    float* deg_in   = ws + (size_t)N;                 // N
    float* s_src    = ws + 2 * (size_t)N;             // N
    float* s_dst    = ws + 3 * (size_t)N;             // N
    _Float16* P_src = (_Float16*)(ws + 4 * (size_t)N);        // N*128 fp16
    _Float16* P_dst = P_src + (size_t)N * 128;                // N*128 fp16
    float* partials = (float*)(P_dst + (size_t)N * 128);      // 2*NPART
    float* inv_nrm  = partials + 2 * NPART;                   // 2
    _Float16* w16o  = (_Float16*)(partials + 2 * NPART + 16); // 4096 f16 (16B-aligned)
    _Float16* w16i  = w16o + 4096;                            // 4096 f16
    // Slice histograms (~12.8 MB) alias the P_src region (25.6 MB): dead
    // before k_nodes writes P_src/P_dst.
    unsigned int* scr = (unsigned int*)P_src;

    dim3 hgrid(S, 2 * NQUART);
    k_hist<<<hgrid, 256, (size_t)Wd * 4, stream>>>(eidx, scr, N, E, Q, Wd, chunk);
    k_fold<<<NPART, 256, 0, stream>>>(scr, deg_out, deg_in, partials, N, Q, Wd, S);
    k_finish<<<1, 256, 0, stream>>>(partials, inv_nrm, W_in, W_out, w16i, w16o);
    k_nodes<<<(N + 63) / 64, 256, 0, stream>>>(z_in, z_out, z_self, w16i, w16o,
                                               b_in, b_out, deg_out, deg_in,
                                               inv_nrm, P_src, P_dst,
                                               s_src, s_dst, N);
    {
        int groups = (E + 1) / 2;
        int blocks = (groups + 15) / 16;
        k_edges<<<blocks, 256, 0, stream>>>(eidx, P_src, P_dst,
                                            s_src, s_dst, (float*)d_out, E);
    }
}